// Round 3
// baseline (763.438 us; speedup 1.0000x reference)
//
#include <hip/hip_runtime.h>

// x[t,b,h] = input·W_ihT + b_ih + hidden·W_hhT + b_hh  (M=32768, N=512, K=512+512)
// then in-place LIF scan over t.
// ARITHMETIC IS BIT-IDENTICAL TO THE ROUND-1 PASSING KERNEL: per output,
// ascending-k fmaf chain per phase (acc1: input·W_ih, acc2: hidden·W_hh),
// epilogue ((acc1 + b_ih) + acc2) + b_hh. Only scheduling/layout changed.

constexpr int Mtot = 32768;

// ---- staging helpers (values unaffected by layout) ----
// LDS: A tile [128][32] f32, W tile [64][32] f32, 16B chunks XOR-swizzled:
//   A: chunk ^= row & 7      (reads are quarter-wave broadcasts -> free)
//   W: chunk ^= (row>>2) & 7 (reads: tn&7 spans all 8 chunks -> 2-way, free)

#define STAGE_STORE()                                                         \
    _Pragma("unroll") for (int q = 0; q < 4; ++q) *(float4*)(As + awr[q]) = ar[q]; \
    _Pragma("unroll") for (int q = 0; q < 2; ++q) *(float4*)(Ws + wwr[q]) = wr[q];

#define STAGE_LOAD(AP, WP)                                                    \
    _Pragma("unroll") for (int q = 0; q < 4; ++q) ar[q] = *(const float4*)((AP) + aoff[q]); \
    _Pragma("unroll") for (int q = 0; q < 2; ++q) wr[q] = *(const float4*)((WP) + woff[q]);

// Inner fma block: per k-chunk kc (4 k's), per acc element the fma order is
// k4+0,1,2,3 (xyzw), kc ascending — identical chain to round 1.
#define FMA_PHASE(ACC)                                                        \
    _Pragma("unroll")                                                         \
    for (int kc = 0; kc < 8; ++kc) {                                          \
        float4 w4[4];                                                         \
        _Pragma("unroll")                                                     \
        for (int j = 0; j < 4; ++j)                                           \
            w4[j] = *(const float4*)((const char*)Ws + tn * 512 + j * 128 + (((kc ^ tn) & 7) << 4)); \
        _Pragma("unroll")                                                     \
        for (int i = 0; i < 8; ++i) {                                         \
            float4 a4 = *(const float4*)((const char*)As + (tm * 8 + i) * 128 + ((kc ^ i) << 4)); \
            _Pragma("unroll")                                                 \
            for (int j = 0; j < 4; ++j) {                                     \
                ACC[i][j] = fmaf(a4.x, w4[j].x, ACC[i][j]);                   \
                ACC[i][j] = fmaf(a4.y, w4[j].y, ACC[i][j]);                   \
                ACC[i][j] = fmaf(a4.z, w4[j].z, ACC[i][j]);                   \
                ACC[i][j] = fmaf(a4.w, w4[j].w, ACC[i][j]);                   \
            }                                                                 \
        }                                                                     \
    }

__global__ __launch_bounds__(256, 3) void gemm_x(
    const float* __restrict__ input, const float* __restrict__ hidden,
    const float* __restrict__ W_ih, const float* __restrict__ b_ih,
    const float* __restrict__ W_hh, const float* __restrict__ b_hh,
    float* __restrict__ out)
{
    __shared__ __align__(16) float As[128 * 32];   // 16 KiB
    __shared__ __align__(16) float Ws[64 * 32];    // 8 KiB

    const int tid = threadIdx.x;
    // XCD-chunked swizzle: XCD x owns 256 consecutive tiles; the 8 bn-tiles
    // sharing an A-tile are dispatch-adjacent within one XCD's L2.
    const int tile = ((blockIdx.x & 7) << 8) | (blockIdx.x >> 3);
    const int bm = tile >> 3, bn = tile & 7;       // 256 x 8 tiles of 128x64
    const int m0 = bm * 128, n0 = bn * 64;
    const int tm = tid >> 4, tn = tid & 15;        // 8x4 outputs per thread

    int aoff[4], awr[4], woff[2], wwr[2];
#pragma unroll
    for (int q = 0; q < 4; ++q) {
        int lin = q * 256 + tid, row = lin >> 3, s4 = lin & 7;
        aoff[q] = (m0 + row) * 512 + s4 * 4;
        awr[q]  = row * 32 + ((s4 ^ (row & 7)) << 2);
    }
#pragma unroll
    for (int q = 0; q < 2; ++q) {
        int lin = q * 256 + tid, row = lin >> 3, s4 = lin & 7;
        woff[q] = (n0 + row) * 512 + s4 * 4;
        wwr[q]  = row * 32 + ((s4 ^ ((row >> 2) & 7)) << 2);
    }

    float acc1[8][4], acc2[8][4];
#pragma unroll
    for (int i = 0; i < 8; ++i)
#pragma unroll
        for (int j = 0; j < 4; ++j) { acc1[i][j] = 0.f; acc2[i][j] = 0.f; }

    float4 ar[4], wr[2];
    STAGE_LOAD(input, W_ih);                       // tile kt=0

    // Phase 1: input · W_ih^T  (K-tiles ascending)
#pragma unroll 1
    for (int kt = 0; kt < 16; ++kt) {
        STAGE_STORE();
        __syncthreads();
        const float* An = (kt < 15) ? (input + (kt + 1) * 32) : hidden;
        const float* Wn = (kt < 15) ? (W_ih + (kt + 1) * 32) : W_hh;
        STAGE_LOAD(An, Wn);                        // overlaps fma phase
        FMA_PHASE(acc1);
        __syncthreads();
    }
    // Phase 2: hidden · W_hh^T
#pragma unroll 1
    for (int kt = 0; kt < 16; ++kt) {
        STAGE_STORE();
        __syncthreads();
        if (kt < 15) {
            const float* An = hidden + (kt + 1) * 32;
            const float* Wn = W_hh + (kt + 1) * 32;
            STAGE_LOAD(An, Wn);
        }
        FMA_PHASE(acc2);
        __syncthreads();
    }

    // Epilogue: x = ((dot1 + b_ih) + dot2) + b_hh  (exact round-1 association)
    const float4 bi4 = *(const float4*)(b_ih + n0 + tn * 4);
    const float4 bh4 = *(const float4*)(b_hh + n0 + tn * 4);
#pragma unroll
    for (int i = 0; i < 8; ++i) {
        float4 o;
        o.x = ((acc1[i][0] + bi4.x) + acc2[i][0]) + bh4.x;
        o.y = ((acc1[i][1] + bi4.y) + acc2[i][1]) + bh4.y;
        o.z = ((acc1[i][2] + bi4.z) + acc2[i][2]) + bh4.z;
        o.w = ((acc1[i][3] + bi4.w) + acc2[i][3]) + bh4.w;
        *(float4*)(out + (size_t)(m0 + tm * 8 + i) * 512 + n0 + tn * 4) = o;
    }
}

// In-place LIF scan: one thread per (b,h) lane, sequential over t.
// Same per-element float ops as round 1 (deeper unroll only changes scheduling).
__global__ __launch_bounds__(256) void lif_scan(float* __restrict__ x)
{
    const int tid = blockIdx.x * blockDim.x + threadIdx.x;  // 0..32767
    float v = 0.f;
    for (int tb = 0; tb < 512; tb += 16) {
        float xv[16];
#pragma unroll
        for (int u = 0; u < 16; ++u)
            xv[u] = x[(tb + u) * 32768 + tid];
#pragma unroll
        for (int u = 0; u < 16; ++u) {
            v = v + (xv[u] - v) * 0.5f;
            float s = (v - 1.0f >= 0.0f) ? 1.0f : 0.0f;
            x[(tb + u) * 32768 + tid] = s;
            v = (1.0f - s) * v;
        }
    }
}

extern "C" void kernel_launch(void* const* d_in, const int* in_sizes, int n_in,
                              void* d_out, int out_size, void* d_ws, size_t ws_size,
                              hipStream_t stream) {
    const float* input  = (const float*)d_in[0];
    const float* hidden = (const float*)d_in[1];
    const float* W_ih   = (const float*)d_in[2];
    const float* b_ih   = (const float*)d_in[3];
    const float* W_hh   = (const float*)d_in[4];
    const float* b_hh   = (const float*)d_in[5];
    float* out = (float*)d_out;

    gemm_x<<<dim3(2048), dim3(256), 0, stream>>>(
        input, hidden, W_ih, b_ih, W_hh, b_hh, out);
    lif_scan<<<dim3(128), dim3(256), 0, stream>>>(out);
}